// Round 2
// baseline (86.019 us; speedup 1.0000x reference)
//
#include <hip/hip_runtime.h>
#include <hip/hip_bf16.h>

// ShuffleNet fused block-MLP for MI355X (gfx950).  R2: np-split x4 for occupancy.
// x:(8192,1024) f32; w1:(16,256,64); b1:(4096); w2:(16,64,256); b2:(1024); y f32.
// h[b,n,o] = sum_i x[b, n*64+i] * w1[n,o,i]
// shuffled j = o*16+n ; g = gelu(h2 + b1)
// y[b, n'*64+o'] = sum_{i'} g[b, n'*256+i'] * w2[n',o',i'] + b2
//   with n'*256+i' = o*16+n  =>  o = n'*16 + (i'>>4), n = i'&15.
// Grid 1024 = 256 rowtiles x 4 np-quarters; each WG: 32 rows, np in [q*4, q*4+4).
// 4 WGs/CU (VGPR 64, LDS 33.8KB) -> 32 waves/CU; 1 barrier per np-iter
// (double-buffered LDS chunk; reuse at it+2 protected by barrier at it+1).

#define LDSK 264   // 256 + 8 pad (keeps 16B align, 4-bank row rotation)
#define CHUNK (32 * LDSK)

typedef __attribute__((ext_vector_type(8))) short  short8;   // 8 bf16 = 4 VGPR
typedef __attribute__((ext_vector_type(4))) short  short4v;
typedef __attribute__((ext_vector_type(4))) float  floatx4;

__device__ __forceinline__ short f2bf(float f) {
  union { __hip_bfloat16 h; short s; } u;
  u.h = __float2bfloat16(f);
  return u.s;
}

// gelu(v) ~= v * sigmoid(1.5957691 * (v + 0.044715 v^3))  (abs err < 5e-4,
// negligible vs bf16 rounding and the 3.09e-3 threshold)
__device__ __forceinline__ float gelu_f(float v) {
  float v2 = v * v;
  float p  = fmaf(0.044715f, v2, 1.0f);
  float t  = v * p;
  float e  = __expf(-1.5957691f * t);
  return v * __builtin_amdgcn_rcpf(1.0f + e);
}

// ---- prep: pack w1 into GEMM1 A-fragment order (bf16) ----
// frag (n, np, ks): lane l elem e = w1[n][np*16 + (l&15)][ks*32 + (l>>4)*8 + e]
__global__ void pack_w1_k(const float* __restrict__ w1, short* __restrict__ w1p) {
  const int t = blockIdx.x * blockDim.x + threadIdx.x;  // 32768
  const int lane = t & 63, ks = (t >> 6) & 1, np = (t >> 7) & 15, n = (t >> 11) & 15;
  const int o  = np * 16 + (lane & 15);
  const int kb = ks * 32 + (lane >> 4) * 8;
  const float* src = w1 + ((size_t)(n * 256 + o) * 64 + kb);
  short8 f;
#pragma unroll
  for (int e = 0; e < 8; ++e) f[e] = f2bf(src[e]);
  *(short8*)(w1p + (size_t)t * 8) = f;
}

// ---- prep: pack w2 into GEMM2 B-fragment order with shuffle folded in ----
// frag (np, ks, ot): lane l elem e: k = ks*32+(l>>4)*8+e; n=k>>4; ohi=k&15;
//   value = w2[np][ot*16+(l&15)][ohi*16 + n]
__global__ void pack_w2_k(const float* __restrict__ w2, short* __restrict__ w2p) {
  const int t = blockIdx.x * blockDim.x + threadIdx.x;  // 32768
  const int lane = t & 63, ot = (t >> 6) & 3, ks = (t >> 8) & 7, np = (t >> 11) & 15;
  const int op = ot * 16 + (lane & 15);
  short8 f;
#pragma unroll
  for (int e = 0; e < 8; ++e) {
    const int k = ks * 32 + (lane >> 4) * 8 + e;
    const int n = k >> 4, ohi = k & 15;
    f[e] = f2bf(w2[(size_t)(np * 64 + op) * 256 + ohi * 16 + n]);
  }
  *(short8*)(w2p + (size_t)t * 8) = f;
}

// ---- fused main: 1024 WGs x 512 threads (8 waves), 32 rows x 4 np per WG ----
__global__ __launch_bounds__(512, 8) void fused_k(
    const float* __restrict__ x, const float* __restrict__ b1,
    const float* __restrict__ b2, const short* __restrict__ w1p,
    const short* __restrict__ w2p, float* __restrict__ y) {
  __shared__ __align__(16) short hlds[2 * CHUNK];   // double-buffered 32x256 chunk

  const int tid  = threadIdx.x;
  const int wv   = tid >> 6;      // wave 0..7
  const int lane = tid & 63;
  const int l15  = lane & 15;
  const int lhi  = lane >> 4;     // 0..3
  const int q    = blockIdx.x & 3;          // np-quarter
  const int row0 = (blockIdx.x >> 2) * 32;  // rowtile
  const int np0  = q * 4;

  // prologue: x fragments for this wave's 2 blocks, 2 ksteps x 2 row-tiles.
  // GEMM1 B-operand: lane l: row(col) = l&15, k = (l>>4)*8 + e (contiguous).
  short8 xf[2][2][2];
#pragma unroll
  for (int bi = 0; bi < 2; ++bi) {
    const int n = 2 * wv + bi;
#pragma unroll
    for (int ks = 0; ks < 2; ++ks) {
#pragma unroll
      for (int rt = 0; rt < 2; ++rt) {
        const float* px = x + (size_t)(row0 + rt * 16 + l15) * 1024 + n * 64 + ks * 32 + lhi * 8;
        floatx4 a = *(const floatx4*)px;
        floatx4 b = *(const floatx4*)(px + 4);
        short8 f;
#pragma unroll
        for (int e = 0; e < 4; ++e) { f[e] = f2bf(a[e]); f[e + 4] = f2bf(b[e]); }
        xf[bi][ks][rt] = f;
      }
    }
  }

  const int rt2 = wv & 1;   // GEMM2: row-tile
  const int ot2 = wv >> 1;  // GEMM2: o'-tile (0..3)

#pragma unroll
  for (int it = 0; it < 4; ++it) {
    const int np = np0 + it;
    short* buf = hlds + (it & 1) * CHUNK;

    // prefetch GEMM2 B-frags (global, L2/L3-resident) to hide under phase A
    short8 bf[8];
#pragma unroll
    for (int ks = 0; ks < 8; ++ks)
      bf[ks] = *(const short8*)(w2p + (size_t)(((np * 8 + ks) * 4 + ot2) * 64 + lane) * 8);

    // ---- phase A: GEMM1 for o-tile np, this wave's 2 n-blocks ----
#pragma unroll
    for (int bi = 0; bi < 2; ++bi) {
      const int n = 2 * wv + bi;
      short8 wf0 = *(const short8*)(w1p + (size_t)(((n * 16 + np) * 2 + 0) * 64 + lane) * 8);
      short8 wf1 = *(const short8*)(w1p + (size_t)(((n * 16 + np) * 2 + 1) * 64 + lane) * 8);
      float bias[4];
#pragma unroll
      for (int r = 0; r < 4; ++r)
        bias[r] = b1[np * 256 + (lhi * 4 + r) * 16 + n];  // b1[o*16+n]
#pragma unroll
      for (int rt = 0; rt < 2; ++rt) {
        floatx4 acc = {0.f, 0.f, 0.f, 0.f};
        acc = __builtin_amdgcn_mfma_f32_16x16x32_bf16(wf0, xf[bi][0][rt], acc, 0, 0, 0);
        acc = __builtin_amdgcn_mfma_f32_16x16x32_bf16(wf1, xf[bi][1][rt], acc, 0, 0, 0);
        short4v hv;
#pragma unroll
        for (int r = 0; r < 4; ++r)
          hv[r] = f2bf(gelu_f(acc[r] + bias[r]));
        // chunk k-index = n*16 + o_local
        *(short4v*)(&buf[(rt * 16 + l15) * LDSK + n * 16 + lhi * 4]) = hv;
      }
    }
    __syncthreads();

    // ---- phase B: GEMM2 block np -> y[:, np*64 .. np*64+64) ----
    floatx4 a0 = {0.f, 0.f, 0.f, 0.f}, a1 = {0.f, 0.f, 0.f, 0.f};
    const short* arow = &buf[(rt2 * 16 + l15) * LDSK + lhi * 8];
#pragma unroll
    for (int ks = 0; ks < 8; ks += 2) {
      short8 f0 = *(const short8*)(arow + ks * 32);
      short8 f1 = *(const short8*)(arow + ks * 32 + 32);
      a0 = __builtin_amdgcn_mfma_f32_16x16x32_bf16(f0, bf[ks], a0, 0, 0, 0);
      a1 = __builtin_amdgcn_mfma_f32_16x16x32_bf16(f1, bf[ks + 1], a1, 0, 0, 0);
    }
    const int col = np * 64 + ot2 * 16 + l15;
    const float bb = b2[col];
    float* py = y + (size_t)(row0 + rt2 * 16 + lhi * 4) * 1024 + col;
#pragma unroll
    for (int r = 0; r < 4; ++r)
      py[(size_t)r * 1024] = a0[r] + a1[r] + bb;
    // no trailing barrier: next iter writes the other buffer; reuse of this
    // buffer at it+2 is ordered by the barrier at it+1 (lgkmcnt drain).
  }
}

extern "C" void kernel_launch(void* const* d_in, const int* in_sizes, int n_in,
                              void* d_out, int out_size, void* d_ws, size_t ws_size,
                              hipStream_t stream) {
  const float* x  = (const float*)d_in[0];
  const float* w1 = (const float*)d_in[1];
  const float* b1 = (const float*)d_in[2];
  const float* w2 = (const float*)d_in[3];
  const float* b2 = (const float*)d_in[4];
  float* y = (float*)d_out;

  short* w1p = (short*)d_ws;             // 16*256*64 bf16 = 512 KB
  short* w2p = w1p + 16 * 256 * 64;      // 512 KB

  pack_w1_k<<<64, 512, 0, stream>>>(w1, w1p);
  pack_w2_k<<<64, 512, 0, stream>>>(w2, w2p);
  fused_k<<<1024, 512, 0, stream>>>(x, b1, b2, w1p, w2p, y);
}

// Round 3
// 50.260 us; speedup vs baseline: 1.7115x; 1.7115x over previous
//
#include <hip/hip_runtime.h>
#include <hip/hip_bf16.h>

// ShuffleNet fused block-MLP, MI355X (gfx950).  R3: 256-thr WGs, np-split x2,
// XOR-swizzled LDS chunk, no spills (VGPR budget 128 via launch_bounds(256,4)).
// x:(8192,1024) f32; w1:(16,256,64); b1:(4096); w2:(16,64,256); b2:(1024); y f32.
//   h[b,n,o] = sum_i x[b,n*64+i]*w1[n,o,i];  shuffled j = o*16+n
//   g = gelu(h+b1);  y[b,n'*64+o'] = sum_{i'} g[b,n'*256+i']*w2[n',o',i'] + b2
//   n'*256+i' = o*16+n  =>  o = n'*16+(i'>>4), n = i'&15.
// Per WG: 16 rows, np in [q*8, q*8+8), 8 iters, double-buffered LDS chunk,
// 1 barrier/iter.  Grid 1024 = 512 rowtiles x 2 q  ->  4 WGs/CU, 16 waves/CU.
// LDS swizzle: stored k' = k ^ ((row&3)<<4)  (keeps 8-elem blocks contiguous;
// bank mapping uniform for both b64 writes and b128 reads -> conflict-free).

#define LDSK 256
#define CHUNK (16 * LDSK)

typedef __attribute__((ext_vector_type(8))) short  short8;   // 8 bf16 = 4 VGPR
typedef __attribute__((ext_vector_type(4))) short  short4v;
typedef __attribute__((ext_vector_type(4))) float  floatx4;

__device__ __forceinline__ short f2bf(float f) {
  union { __hip_bfloat16 h; short s; } u;
  u.h = __float2bfloat16(f);
  return u.s;
}

// gelu(v) ~= v * sigmoid(1.5957691*(v + 0.044715 v^3))  (abs err < 5e-4,
// negligible vs bf16 rounding and the 3.09e-3 threshold)
__device__ __forceinline__ float gelu_f(float v) {
  float v2 = v * v;
  float p  = fmaf(0.044715f, v2, 1.0f);
  float t  = v * p;
  float e  = __expf(-1.5957691f * t);
  return v * __builtin_amdgcn_rcpf(1.0f + e);
}

// ---- prep: pack w1 into GEMM1 A-fragment order (bf16) ----
// frag (n, np, ks): lane l elem e = w1[n][np*16 + (l&15)][ks*32 + (l>>4)*8 + e]
__global__ void pack_w1_k(const float* __restrict__ w1, short* __restrict__ w1p) {
  const int t = blockIdx.x * blockDim.x + threadIdx.x;  // 32768
  const int lane = t & 63, ks = (t >> 6) & 1, np = (t >> 7) & 15, n = (t >> 11) & 15;
  const int o  = np * 16 + (lane & 15);
  const int kb = ks * 32 + (lane >> 4) * 8;
  const float* src = w1 + ((size_t)(n * 256 + o) * 64 + kb);
  short8 f;
#pragma unroll
  for (int e = 0; e < 8; ++e) f[e] = f2bf(src[e]);
  *(short8*)(w1p + (size_t)t * 8) = f;
}

// ---- prep: pack w2 into GEMM2 B-fragment order with shuffle folded in ----
// frag (np, ks, ot): lane l elem e: k = ks*32+(l>>4)*8+e; n=k>>4; ohi=k&15;
//   value = w2[np][ot*16+(l&15)][ohi*16 + n]
__global__ void pack_w2_k(const float* __restrict__ w2, short* __restrict__ w2p) {
  const int t = blockIdx.x * blockDim.x + threadIdx.x;  // 32768
  const int lane = t & 63, ot = (t >> 6) & 3, ks = (t >> 8) & 7, np = (t >> 11) & 15;
  const int op = ot * 16 + (lane & 15);
  short8 f;
#pragma unroll
  for (int e = 0; e < 8; ++e) {
    const int k = ks * 32 + (lane >> 4) * 8 + e;
    const int n = k >> 4, ohi = k & 15;
    f[e] = f2bf(w2[(size_t)(np * 64 + op) * 256 + ohi * 16 + n]);
  }
  *(short8*)(w2p + (size_t)t * 8) = f;
}

// ---- fused main: 1024 WGs x 256 threads (4 waves), 16 rows x 8 np per WG ----
__global__ __launch_bounds__(256, 4) void fused_k(
    const float* __restrict__ x, const float* __restrict__ b1,
    const float* __restrict__ b2, const short* __restrict__ w1p,
    const short* __restrict__ w2p, float* __restrict__ y) {
  __shared__ __align__(16) short hlds[2 * CHUNK];   // 16 KB, double-buffered

  const int tid  = threadIdx.x;
  const int wv   = tid >> 6;      // wave 0..3
  const int lane = tid & 63;
  const int l15  = lane & 15;
  const int lhi  = lane >> 4;     // 0..3
  const int q    = blockIdx.x & 1;          // np-half
  const int row0 = (blockIdx.x >> 1) * 16;  // rowtile
  const int np0  = q * 8;
  const int sw   = (l15 & 3) << 4;          // LDS XOR swizzle for this row

  // prologue: x fragments, wave wv owns n = 4*wv + bi (bi 0..3), 2 ksteps.
  // GEMM1 B-operand: lane l: col(row) = l&15, k = (l>>4)*8 + e (contiguous).
  short8 xf[4][2];
#pragma unroll
  for (int bi = 0; bi < 4; ++bi) {
    const int n = 4 * wv + bi;
#pragma unroll
    for (int ks = 0; ks < 2; ++ks) {
      const float* px = x + (size_t)(row0 + l15) * 1024 + n * 64 + ks * 32 + lhi * 8;
      floatx4 a = *(const floatx4*)px;
      floatx4 b = *(const floatx4*)(px + 4);
      short8 f;
#pragma unroll
      for (int e = 0; e < 4; ++e) { f[e] = f2bf(a[e]); f[e + 4] = f2bf(b[e]); }
      xf[bi][ks] = f;
    }
  }

#pragma unroll
  for (int it = 0; it < 8; ++it) {
    const int np = np0 + it;
    short* buf = hlds + (it & 1) * CHUNK;

    // prefetch GEMM2 B-frags (L2-resident) to hide latency under phase A
    short8 bf[8];
#pragma unroll
    for (int ks = 0; ks < 8; ++ks)
      bf[ks] = *(const short8*)(w2p + (size_t)(((np * 8 + ks) * 4 + wv) * 64 + lane) * 8);

    // ---- phase A: GEMM1 for o-tile np, this wave's 4 n-blocks ----
#pragma unroll
    for (int bi = 0; bi < 4; ++bi) {
      const int n = 4 * wv + bi;
      short8 wf0 = *(const short8*)(w1p + (size_t)(((n * 16 + np) * 2 + 0) * 64 + lane) * 8);
      short8 wf1 = *(const short8*)(w1p + (size_t)(((n * 16 + np) * 2 + 1) * 64 + lane) * 8);
      float bias[4];
#pragma unroll
      for (int r = 0; r < 4; ++r)
        bias[r] = b1[np * 256 + (lhi * 4 + r) * 16 + n];  // b1[o*16+n]
      floatx4 acc = {0.f, 0.f, 0.f, 0.f};
      acc = __builtin_amdgcn_mfma_f32_16x16x32_bf16(wf0, xf[bi][0], acc, 0, 0, 0);
      acc = __builtin_amdgcn_mfma_f32_16x16x32_bf16(wf1, xf[bi][1], acc, 0, 0, 0);
      short4v hv;
#pragma unroll
      for (int r = 0; r < 4; ++r)
        hv[r] = f2bf(gelu_f(acc[r] + bias[r]));
      // chunk k = n*16 + o_local (o_local = lhi*4..+4), stored XOR-swizzled
      *(short4v*)(&buf[l15 * LDSK + ((n * 16 + lhi * 4) ^ sw)]) = hv;
    }
    __syncthreads();

    // ---- phase B: GEMM2 block np -> y[:, np*64 .. np*64+64), ot = wv ----
    floatx4 a0 = {0.f, 0.f, 0.f, 0.f}, a1 = {0.f, 0.f, 0.f, 0.f};
    const short* arow = &buf[l15 * LDSK];
#pragma unroll
    for (int ks = 0; ks < 8; ks += 2) {
      short8 f0 = *(const short8*)(arow + (((ks + 0) * 32 + lhi * 8) ^ sw));
      short8 f1 = *(const short8*)(arow + (((ks + 1) * 32 + lhi * 8) ^ sw));
      a0 = __builtin_amdgcn_mfma_f32_16x16x32_bf16(f0, bf[ks], a0, 0, 0, 0);
      a1 = __builtin_amdgcn_mfma_f32_16x16x32_bf16(f1, bf[ks + 1], a1, 0, 0, 0);
    }
    const int col = np * 64 + wv * 16 + l15;
    const float bb = b2[col];
    float* py = y + (size_t)(row0 + lhi * 4) * 1024 + col;
#pragma unroll
    for (int r = 0; r < 4; ++r)
      py[(size_t)r * 1024] = a0[r] + a1[r] + bb;
    // no trailing barrier: next iter uses the other buffer; reuse of this
    // buffer at it+2 is ordered by the barrier at it+1.
  }
}

extern "C" void kernel_launch(void* const* d_in, const int* in_sizes, int n_in,
                              void* d_out, int out_size, void* d_ws, size_t ws_size,
                              hipStream_t stream) {
  const float* x  = (const float*)d_in[0];
  const float* w1 = (const float*)d_in[1];
  const float* b1 = (const float*)d_in[2];
  const float* w2 = (const float*)d_in[3];
  const float* b2 = (const float*)d_in[4];
  float* y = (float*)d_out;

  short* w1p = (short*)d_ws;             // 16*256*64 bf16 = 512 KB
  short* w2p = w1p + 16 * 256 * 64;      // 512 KB

  pack_w1_k<<<64, 512, 0, stream>>>(w1, w1p);
  pack_w2_k<<<64, 512, 0, stream>>>(w2, w2p);
  fused_k<<<1024, 256, 0, stream>>>(x, b1, b2, w1p, w2p, y);
}